// Round 11
// baseline (462.705 us; speedup 1.0000x reference)
//
#include <hip/hip_runtime.h>
#include <cstddef>
#include <cstdint>

// Problem constants (from reference)
static constexpr int Nn    = 20000;
static constexpr int Ee    = 320000;
static constexpr int Vv    = 100;
static constexpr int Hh    = 128;
static constexpr int HEADS = 3;
static constexpr int Bb    = 200;
static constexpr float NEG = 0.2f;
static constexpr float EPS = 1e-5f;

typedef short bf16x8 __attribute__((ext_vector_type(8)));
typedef float f32x4  __attribute__((ext_vector_type(4)));

__device__ inline unsigned short bf16_rne(float x) {
    unsigned u = __builtin_bit_cast(unsigned, x);
    u += 0x7FFFu + ((u >> 16) & 1u);
    return (unsigned short)(u >> 16);
}
__device__ inline float bf16_f(unsigned short h) {
    unsigned u = ((unsigned)h) << 16;
    return __builtin_bit_cast(float, u);
}
__device__ inline float bf_lo(unsigned u) { return __builtin_bit_cast(float, u << 16); }
__device__ inline float bf_hi(unsigned u) { return __builtin_bit_cast(float, u & 0xFFFF0000u); }
__device__ inline float lrelu(float a) { return a >= 0.f ? a : NEG * a; }
__device__ inline float sigmoidf(float x) { return 1.f / (1.f + __expf(-x)); }

// ---------------------------------------------------------------------------
// CSR scan + fill (hist lives in prep_all)
// ---------------------------------------------------------------------------
__global__ __launch_bounds__(1024) void scan_offsets(const int* __restrict__ deg,
                                                     int* __restrict__ offs,
                                                     int* __restrict__ cur) {
    __shared__ int sums[1024];
    const int tid = threadIdx.x;
    const int per = (Nn + 1023) >> 10;
    int begin = tid * per;
    int end = begin + per; if (end > Nn) end = Nn;
    if (begin > Nn) begin = Nn;
    int s = 0;
    for (int i = begin; i < end; i++) s += deg[i];
    sums[tid] = s;
    __syncthreads();
    for (int off = 1; off < 1024; off <<= 1) {
        int v = (tid >= off) ? sums[tid - off] : 0;
        __syncthreads();
        sums[tid] += v;
        __syncthreads();
    }
    int run = sums[tid] - s;
    for (int i = begin; i < end; i++) {
        offs[i] = run; cur[i] = run;
        run += deg[i];
    }
    if (end == Nn) offs[Nn] = run;
}

__global__ void fill_csr(const int* __restrict__ dst, const int* __restrict__ src,
                         int* __restrict__ cur, int* __restrict__ csrc) {
    for (int i = blockIdx.x * blockDim.x + threadIdx.x; i < Ee; i += gridDim.x * blockDim.x) {
        int p = atomicAdd(&cur[dst[i]], 1);
        csrc[p] = src[i];
    }
}

// ---------------------------------------------------------------------------
// Fused prep: projW split; Wfused = blockdiag(Wn)@Ws split-transposed;
// va/vd = Wn_h @ att halves; vc = bn_h . att halves; biasF = convB + bn@Ws;
// GRU weight transposes; graph offsets; dst histogram.
// ---------------------------------------------------------------------------
struct PrepArgs {
    const float *projW, *convWn, *convWs, *convAtt, *convBn, *convB;
    const float *Wih0, *Whh0, *Wih1, *Whh1;
    const int *gid, *dst;
    unsigned short *pBth, *pBtl;
    unsigned short *WfTh0, *WfTl0, *WfTh1, *WfTl1;
    float *vavd, *vc, *biasF;
    float *WihT0, *WhhT0, *WihT1, *WhhT1;
    int *goffs, *deg;
};

__device__ inline void wsplit(const float* B, int K, int N, int idx,
                              unsigned short* Bth, unsigned short* Btl) {
    int k = idx / N, n = idx - k * N;
    float v = B[idx];
    unsigned short h = bf16_rne(v);
    unsigned short l = bf16_rne(v - bf16_f(h));
    Bth[(size_t)n * K + k] = h;
    Btl[(size_t)n * K + k] = l;
}
__device__ inline void gruT(const float* W, int K, int idx, float* WT) {
    int d = idx / (384 * K);
    int r = idx - d * 384 * K;
    int j = r / K, k = r - j * K;
    WT[(size_t)d * K * 384 + (size_t)k * 384 + j] = W[idx];
}

__global__ void prep_all(PrepArgs a) {
    int i = blockIdx.x * blockDim.x + threadIdx.x;
    if (i < 16384) { wsplit(a.projW, 128, 128, i, a.pBth, a.pBtl); return; } i -= 16384;
#pragma unroll
    for (int l = 0; l < 2; l++) {
        if (i < 49152) {
            int k = i >> 7, c = i & 127;
            int h = k >> 7, i_ = k & 127;
            const float* wn = a.convWn + (size_t)l * 49152 + (size_t)i_ * 384 + h * 128;
            const float* ws = a.convWs + (size_t)l * 49152 + (size_t)(h * 128) * 128 + c;
            float v = 0.f;
            for (int j = 0; j < 128; j++) v += wn[j] * ws[(size_t)j * 128];
            unsigned short hi = bf16_rne(v);
            unsigned short lo = bf16_rne(v - bf16_f(hi));
            unsigned short* th = l ? a.WfTh1 : a.WfTh0;
            unsigned short* tl = l ? a.WfTl1 : a.WfTl0;
            th[(size_t)c * 384 + k] = hi;
            tl[(size_t)c * 384 + k] = lo;
            return;
        }
        i -= 49152;
    }
    if (i < 1536) {
        int l = i / 768, r = i % 768;
        int sd = r / 384, rr = r % 384, h = rr >> 7, i_ = rr & 127;
        const float* wn = a.convWn + (size_t)l * 49152 + (size_t)i_ * 384 + h * 128;
        const float* at = a.convAtt + l * 768 + h * 256 + sd * 128;
        float v = 0.f;
        for (int j = 0; j < 128; j++) v += wn[j] * at[j];
        a.vavd[i] = v;
        return;
    } i -= 1536;
    if (i < 12) {
        int l = i / 6, r = i % 6, sd = r / 3, h = r % 3;
        const float* bn = a.convBn + l * 384 + h * 128;
        const float* at = a.convAtt + l * 768 + h * 256 + sd * 128;
        float v = 0.f;
        for (int j = 0; j < 128; j++) v += bn[j] * at[j];
        a.vc[i] = v;
        return;
    } i -= 12;
    if (i < 256) {
        int l = i >> 7, c = i & 127;
        const float* bn = a.convBn + l * 384;
        const float* ws = a.convWs + (size_t)l * 49152 + c;
        float v = a.convB[l * 128 + c];
        for (int k = 0; k < 384; k++) v += bn[k] * ws[(size_t)k * 128];
        a.biasF[i] = v;
        return;
    } i -= 256;
    if (i < 98304)  { gruT(a.Wih0, 128, i, a.WihT0); return; }  i -= 98304;
    if (i < 98304)  { gruT(a.Whh0, 128, i, a.WhhT0); return; }  i -= 98304;
    if (i < 196608) { gruT(a.Wih1, 256, i, a.WihT1); return; }  i -= 196608;
    if (i < 98304)  { gruT(a.Whh1, 128, i, a.WhhT1); return; }  i -= 98304;
    if (i < Nn) {
        int g = a.gid[i];
        if (i == 0) { for (int b = 0; b <= g; b++) a.goffs[b] = 0; }
        else { int pg = a.gid[i - 1]; for (int b = pg + 1; b <= g; b++) a.goffs[b] = i; }
        if (i == Nn - 1) { for (int b = g + 1; b <= Bb; b++) a.goffs[b] = Nn; }
        return;
    } i -= Nn;
    if (i < Ee) atomicAdd(&a.deg[a.dst[i]], 1);
}

// ---------------------------------------------------------------------------
// Split-bf16 MFMA GEMM, BM=32, BN=128, BK=32; 256 threads = 4 waves (1x4),
// wave tile 32x32 (2x2 MFMA 16x16x32). Fused epilogues:
// MODE 0: proj: hcur = acc+bias+projW[wid]; MODE 2: residual+LN+ReLU.
// Both: fused per-graph readout; optional next-layer att dots (register-space)
// + bf16 hcur plane.
// ---------------------------------------------------------------------------
struct GArgs {
    const float* A; const unsigned short* Bth; const unsigned short* Btl;
    const float* bias; int M, K;
    const int* wid; const float* projW;                 // MODE 0
    const int* deg; const float* gamma; const float* beta;  // MODE 2
    float* hcur;
    const int* gid; float* reado;
    const float* vavd; const float* vc;                 // null -> skip dots/hb
    float* adf; float* addf;
    unsigned short* hb;
};

template <int MODE>
__global__ __launch_bounds__(256) void gemm_fused(GArgs a) {
    __shared__ unsigned short As_hi[32][40];
    __shared__ unsigned short As_lo[32][40];
    __shared__ unsigned short Bs_hi[128][40];
    __shared__ unsigned short Bs_lo[128][40];
    __shared__ float ytile[32][132];
    __shared__ float sred[6][32][4];
    __shared__ int sgid[32];
    const int tid  = threadIdx.x;
    const int row0 = blockIdx.y * 32;
    const int wn   = tid >> 6;          // wave 0..3 along N
    const int L    = tid & 63;
    const int lrow = L & 15;
    const int lq   = L >> 4;
    const int K = a.K;

    f32x4 acc[2][2];
#pragma unroll
    for (int i = 0; i < 2; i++)
#pragma unroll
        for (int j = 0; j < 2; j++) acc[i][j] = (f32x4){0.f, 0.f, 0.f, 0.f};

    for (int kb = 0; kb < K; kb += 32) {
        {   // stage A 32x32
            int m  = tid >> 3;
            int kq = (tid & 7) * 4;
            float4 v = *(const float4*)(a.A + (size_t)(row0 + m) * K + kb + kq);
            unsigned short h0 = bf16_rne(v.x), h1 = bf16_rne(v.y),
                           h2 = bf16_rne(v.z), h3 = bf16_rne(v.w);
            *(short4*)&As_hi[m][kq] = make_short4((short)h0, (short)h1, (short)h2, (short)h3);
            *(short4*)&As_lo[m][kq] = make_short4((short)bf16_rne(v.x - bf16_f(h0)),
                                                  (short)bf16_rne(v.y - bf16_f(h1)),
                                                  (short)bf16_rne(v.z - bf16_f(h2)),
                                                  (short)bf16_rne(v.w - bf16_f(h3)));
        }
        {   // stage B^T 128x32
            int n  = tid >> 1;
            int kh = (tid & 1) * 16;
            const unsigned short* sh = a.Bth + (size_t)n * K + kb + kh;
            const unsigned short* sl = a.Btl + (size_t)n * K + kb + kh;
            *(float4*)&Bs_hi[n][kh]     = *(const float4*)sh;
            *(float4*)&Bs_hi[n][kh + 8] = *(const float4*)(sh + 8);
            *(float4*)&Bs_lo[n][kh]     = *(const float4*)sl;
            *(float4*)&Bs_lo[n][kh + 8] = *(const float4*)(sl + 8);
        }
        __syncthreads();
        bf16x8 ah[2], al[2], bh[2], bl[2];
#pragma unroll
        for (int mi = 0; mi < 2; mi++) {
            int r = mi * 16 + lrow;
            ah[mi] = *(const bf16x8*)&As_hi[r][lq * 8];
            al[mi] = *(const bf16x8*)&As_lo[r][lq * 8];
        }
#pragma unroll
        for (int ni = 0; ni < 2; ni++) {
            int r = wn * 32 + ni * 16 + lrow;
            bh[ni] = *(const bf16x8*)&Bs_hi[r][lq * 8];
            bl[ni] = *(const bf16x8*)&Bs_lo[r][lq * 8];
        }
#pragma unroll
        for (int mi = 0; mi < 2; mi++)
#pragma unroll
            for (int ni = 0; ni < 2; ni++) {
                acc[mi][ni] = __builtin_amdgcn_mfma_f32_16x16x32_bf16(ah[mi], bh[ni], acc[mi][ni], 0, 0, 0);
                acc[mi][ni] = __builtin_amdgcn_mfma_f32_16x16x32_bf16(ah[mi], bl[ni], acc[mi][ni], 0, 0, 0);
                acc[mi][ni] = __builtin_amdgcn_mfma_f32_16x16x32_bf16(al[mi], bh[ni], acc[mi][ni], 0, 0, 0);
            }
        __syncthreads();
    }

    // bias
#pragma unroll
    for (int ni = 0; ni < 2; ni++) {
        float bb = a.bias[wn * 32 + ni * 16 + lrow];
#pragma unroll
        for (int mi = 0; mi < 2; mi++)
#pragma unroll
            for (int r = 0; r < 4; r++) acc[mi][ni][r] += bb;
    }

    if constexpr (MODE == 0) {
#pragma unroll
        for (int mi = 0; mi < 2; mi++)
#pragma unroll
            for (int r = 0; r < 4; r++) {
                int lr = mi * 16 + lq * 4 + r;
                int row = row0 + lr;
                int wi = a.wid[row];
#pragma unroll
                for (int ni = 0; ni < 2; ni++) {
                    int c = wn * 32 + ni * 16 + lrow;
                    float y = acc[mi][ni][r] + a.projW[(size_t)wi * 128 + c];
                    acc[mi][ni][r] = y;
                    a.hcur[(size_t)row * 128 + c] = y;
                    ytile[lr][c] = y;
                }
            }
    }

    if constexpr (MODE == 2) {
        __shared__ float red1[32][4], red2[32][4];
        float g4[2], be4[2];
#pragma unroll
        for (int ni = 0; ni < 2; ni++) {
            int c = wn * 32 + ni * 16 + lrow;
            g4[ni] = a.gamma[c]; be4[ni] = a.beta[c];
        }
#pragma unroll
        for (int mi = 0; mi < 2; mi++)
#pragma unroll
            for (int r = 0; r < 4; r++) {
                int lr = mi * 16 + lq * 4 + r;
                int row = row0 + lr;
                int dg = a.deg[row];
#pragma unroll
                for (int ni = 0; ni < 2; ni++) {
                    int c = wn * 32 + ni * 16 + lrow;
                    float hold = a.hcur[(size_t)row * 128 + c];
                    acc[mi][ni][r] = hold + (dg > 0 ? acc[mi][ni][r] : 0.f);
                }
            }
#pragma unroll
        for (int mi = 0; mi < 2; mi++)
#pragma unroll
            for (int r = 0; r < 4; r++) {
                float ps = acc[mi][0][r] + acc[mi][1][r];
#pragma unroll
                for (int o = 1; o < 16; o <<= 1) ps += __shfl_xor(ps, o, 64);
                if (lrow == 0) red1[mi * 16 + lq * 4 + r][wn] = ps;
            }
        __syncthreads();
#pragma unroll
        for (int mi = 0; mi < 2; mi++)
#pragma unroll
            for (int r = 0; r < 4; r++) {
                int lr = mi * 16 + lq * 4 + r;
                float mu = (red1[lr][0] + red1[lr][1] + red1[lr][2] + red1[lr][3]) * (1.f / 128.f);
                float qs = 0.f;
#pragma unroll
                for (int ni = 0; ni < 2; ni++) {
                    float dx = acc[mi][ni][r] - mu;
                    qs += dx * dx;
                }
#pragma unroll
                for (int o = 1; o < 16; o <<= 1) qs += __shfl_xor(qs, o, 64);
                if (lrow == 0) red2[lr][wn] = qs;
            }
        __syncthreads();
#pragma unroll
        for (int mi = 0; mi < 2; mi++)
#pragma unroll
            for (int r = 0; r < 4; r++) {
                int lr = mi * 16 + lq * 4 + r;
                int row = row0 + lr;
                float mu = (red1[lr][0] + red1[lr][1] + red1[lr][2] + red1[lr][3]) * (1.f / 128.f);
                float var = (red2[lr][0] + red2[lr][1] + red2[lr][2] + red2[lr][3]) * (1.f / 128.f);
                float rs = rsqrtf(var + EPS);
#pragma unroll
                for (int ni = 0; ni < 2; ni++) {
                    int c = wn * 32 + ni * 16 + lrow;
                    float y = fmaxf((acc[mi][ni][r] - mu) * rs * g4[ni] + be4[ni], 0.f);
                    acc[mi][ni][r] = y;
                    a.hcur[(size_t)row * 128 + c] = y;
                    ytile[lr][c] = y;
                }
            }
    }

    if (tid < 32) sgid[tid] = a.gid[row0 + tid];

    // register-space attention dots
    const bool dots = (a.vavd != nullptr);
    if (dots) {
        float vv0[6], vv1[6];
#pragma unroll
        for (int d = 0; d < 6; d++) {
            vv0[d] = a.vavd[d * 128 + wn * 32 + lrow];
            vv1[d] = a.vavd[d * 128 + wn * 32 + 16 + lrow];
        }
#pragma unroll
        for (int d = 0; d < 6; d++) {
#pragma unroll
            for (int mi = 0; mi < 2; mi++)
#pragma unroll
                for (int r = 0; r < 4; r++) {
                    float ps = acc[mi][0][r] * vv0[d] + acc[mi][1][r] * vv1[d];
#pragma unroll
                    for (int o = 1; o < 16; o <<= 1) ps += __shfl_xor(ps, o, 64);
                    if (lrow == 0) sred[d][mi * 16 + lq * 4 + r][wn] = ps;
                }
        }
    }
    __syncthreads();

    // fused per-graph readout (gid sorted -> runs, atomic per run)
    {
        int j = tid & 127, hh = tid >> 7;
        float sum = 0.f; int curg = -1;
        for (int r = hh * 16; r < hh * 16 + 16; r++) {
            int g = sgid[r];
            if (g != curg) {
                if (curg >= 0) atomicAdd(&a.reado[(size_t)curg * 128 + j], sum);
                sum = 0.f; curg = g;
            }
            sum += ytile[r][j];
        }
        if (curg >= 0) atomicAdd(&a.reado[(size_t)curg * 128 + j], sum);
    }

    if (dots) {
        if (tid < 192) {
            int row = tid & 31, d = tid >> 5;     // d in [0,6)
            float s = sred[d][row][0] + sred[d][row][1] + sred[d][row][2] + sred[d][row][3]
                    + a.vc[d];
            int node = row0 + row;
            int sd = d / 3, h = d - sd * 3;
            float* dstp = sd ? a.addf : a.adf;
            dstp[(size_t)node * 4 + h] = s;
        }
        {   // bf16 hcur plane from ytile
            int row = tid >> 3, c0 = (tid & 7) * 16;
            unsigned* dst = (unsigned*)(a.hb + (size_t)(row0 + row) * 128 + c0);
#pragma unroll
            for (int q = 0; q < 8; q++) {
                unsigned lo = bf16_rne(ytile[row][c0 + 2 * q]);
                unsigned hi = bf16_rne(ytile[row][c0 + 2 * q + 1]);
                dst[q] = lo | (hi << 16);
            }
        }
    }
}

// ---------------------------------------------------------------------------
// GAT gather: one wave per dst node, bf16 hcur rows (256B), scores from dots.
// ---------------------------------------------------------------------------
__global__ __launch_bounds__(256) void gat_gather(const unsigned short* __restrict__ hb,
                                                  const float4* __restrict__ ad,
                                                  const float4* __restrict__ add,
                                                  const int* __restrict__ offs,
                                                  const int* __restrict__ csrc,
                                                  float* __restrict__ T) {
    __shared__ float4 slot[4][64];
    const int n = (blockIdx.x * 256 + threadIdx.x) >> 6;
    const int wv_ = threadIdx.x >> 6;
    const int L = threadIdx.x & 63;
    if (n >= Nn) return;
    const int start = offs[n];
    const int deg = offs[n + 1] - start;
    float2* o2 = (float2*)(T + (size_t)n * 384);
    if (deg == 0) {
        float2 z = make_float2(0.f, 0.f);
        o2[L] = z; o2[64 + L] = z; o2[128 + L] = z;
        return;
    }
    const float4 adn = add[n];
    float2 t0 = make_float2(0.f, 0.f), t1 = t0, t2 = t0;

    if (deg <= 64) {
        int sn = 0; float e0 = 0.f, e1 = 0.f, e2 = 0.f;
        if (L < deg) {
            sn = csrc[start + L];
            float4 a4 = ad[sn];
            e0 = __expf(lrelu(a4.x + adn.x));
            e1 = __expf(lrelu(a4.y + adn.y));
            e2 = __expf(lrelu(a4.z + adn.z));
        }
        float s0 = e0, s1 = e1, s2 = e2;
#pragma unroll
        for (int o = 32; o > 0; o >>= 1) {
            s0 += __shfl_xor(s0, o, 64);
            s1 += __shfl_xor(s1, o, 64);
            s2 += __shfl_xor(s2, o, 64);
        }
        slot[wv_][L] = make_float4(__builtin_bit_cast(float, sn),
                                   e0 / s0, e1 / s1, e2 / s2);
        __builtin_amdgcn_wave_barrier();
#pragma unroll 2
        for (int j = 0; j < deg; j++) {
            float4 sc = slot[wv_][j];
            int s_n = __builtin_bit_cast(int, sc.x);
            unsigned u = ((const unsigned*)(hb + (size_t)s_n * 128))[L];
            float x0 = bf_lo(u), x1 = bf_hi(u);
            t0.x += sc.y * x0; t0.y += sc.y * x1;
            t1.x += sc.z * x0; t1.y += sc.z * x1;
            t2.x += sc.w * x0; t2.y += sc.w * x1;
        }
    } else {
        float s0 = 0.f, s1 = 0.f, s2 = 0.f;
        for (int i = L; i < deg; i += 64) {
            int sn = csrc[start + i];
            float4 a4 = ad[sn];
            s0 += __expf(lrelu(a4.x + adn.x));
            s1 += __expf(lrelu(a4.y + adn.y));
            s2 += __expf(lrelu(a4.z + adn.z));
        }
#pragma unroll
        for (int o = 32; o > 0; o >>= 1) {
            s0 += __shfl_xor(s0, o, 64);
            s1 += __shfl_xor(s1, o, 64);
            s2 += __shfl_xor(s2, o, 64);
        }
        float i0 = 1.f / s0, i1 = 1.f / s1, i2 = 1.f / s2;
        for (int base = 0; base < deg; base += 64) {
            int cnt = deg - base; if (cnt > 64) cnt = 64;
            if (L < cnt) {
                int sn = csrc[start + base + L];
                float4 a4 = ad[sn];
                slot[wv_][L] = make_float4(__builtin_bit_cast(float, sn),
                                           __expf(lrelu(a4.x + adn.x)) * i0,
                                           __expf(lrelu(a4.y + adn.y)) * i1,
                                           __expf(lrelu(a4.z + adn.z)) * i2);
            }
            __builtin_amdgcn_wave_barrier();
            for (int j = 0; j < cnt; j++) {
                float4 sc = slot[wv_][j];
                int s_n = __builtin_bit_cast(int, sc.x);
                unsigned u = ((const unsigned*)(hb + (size_t)s_n * 128))[L];
                float x0 = bf_lo(u), x1 = bf_hi(u);
                t0.x += sc.y * x0; t0.y += sc.y * x1;
                t1.x += sc.z * x0; t1.y += sc.z * x1;
                t2.x += sc.w * x0; t2.y += sc.w * x1;
            }
            __builtin_amdgcn_wave_barrier();
        }
    }
    o2[L] = t0; o2[64 + L] = t1; o2[128 + L] = t2;
}

// ---------------------------------------------------------------------------
// GRU helpers: 8-deep double-buffered prefetch dots (loads stay in flight;
// accumulator chains split for ILP — fp reassociation is below threshold).
// ---------------------------------------------------------------------------
template <int K>
__device__ inline void gi3_dot(const float* __restrict__ W, int j,
                               const float* __restrict__ x0,
                               const float* __restrict__ x1,
                               const float* __restrict__ x2,
                               float& g0, float& g1, float& g2) {
    float buf[8], nxt[8];
#pragma unroll
    for (int u = 0; u < 8; u++) buf[u] = W[(size_t)u * 384 + j];
    float a0[2] = {0.f, 0.f}, a1[2] = {0.f, 0.f}, a2[2] = {0.f, 0.f};
    for (int k0 = 0; k0 < K; k0 += 8) {
        if (k0 + 8 < K) {
#pragma unroll
            for (int u = 0; u < 8; u++) nxt[u] = W[(size_t)(k0 + 8 + u) * 384 + j];
        }
#pragma unroll
        for (int u = 0; u < 8; u++) {
            float w = buf[u];
            a0[u & 1] += w * x0[k0 + u];
            a1[u & 1] += w * x1[k0 + u];
            a2[u & 1] += w * x2[k0 + u];
        }
#pragma unroll
        for (int u = 0; u < 8; u++) buf[u] = nxt[u];
    }
    g0 += a0[0] + a0[1]; g1 += a1[0] + a1[1]; g2 += a2[0] + a2[1];
}

__device__ inline float dot128_pf(const float* __restrict__ W, int j,
                                  const float* __restrict__ hsv) {
    float buf[8], nxt[8];
#pragma unroll
    for (int u = 0; u < 8; u++) buf[u] = W[(size_t)u * 384 + j];
    float a[8] = {0.f, 0.f, 0.f, 0.f, 0.f, 0.f, 0.f, 0.f};
    for (int k0 = 0; k0 < 128; k0 += 8) {
        if (k0 + 8 < 128) {
#pragma unroll
            for (int u = 0; u < 8; u++) nxt[u] = W[(size_t)(k0 + 8 + u) * 384 + j];
        }
#pragma unroll
        for (int u = 0; u < 8; u++) a[u] += buf[u] * hsv[k0 + u];
#pragma unroll
        for (int u = 0; u < 8; u++) buf[u] = nxt[u];
    }
    return ((a[0] + a[1]) + (a[2] + a[3])) + ((a[4] + a[5]) + (a[6] + a[7]));
}

// ---------------------------------------------------------------------------
// Full GRU stack: one block per batch element, 768 threads (2 dirs x 384).
// ---------------------------------------------------------------------------
__global__ __launch_bounds__(768) void gru_all(const float* __restrict__ reado,
                                               const int* __restrict__ goffs,
                                               const float* __restrict__ WihT0,
                                               const float* __restrict__ WhhT0,
                                               const float* __restrict__ bih0,
                                               const float* __restrict__ bhh0,
                                               const float* __restrict__ WihT1,
                                               const float* __restrict__ WhhT1,
                                               const float* __restrict__ bih1,
                                               const float* __restrict__ bhh1,
                                               float* __restrict__ out) {
    const int b = blockIdx.x;
    const int tid = threadIdx.x;
    const int dir = tid / 384;
    const int j = tid - dir * 384;
    __shared__ float xs[3][128];
    __shared__ float y0s[3][256];
    __shared__ float hs[2][128];
    __shared__ float gil[2][384], ghl[2][384];
    __shared__ float fin01[2][128];
    if (tid < 128) {
        int cnt = goffs[b + 1] - goffs[b];
        float invc = 1.f / fmaxf((float)cnt, 1.f);
#pragma unroll
        for (int t = 0; t < 3; t++)
            xs[t][tid] = reado[(size_t)t * Bb * Hh + (size_t)b * Hh + tid] * invc;
    }
    if (j < 128) hs[dir][j] = 0.f;
    __syncthreads();
    {
        const float* Wi = WihT0 + (size_t)dir * 128 * 384;
        const float* Wh = WhhT0 + (size_t)dir * 128 * 384;
        float gi[3];
        gi[0] = gi[1] = gi[2] = bih0[dir * 384 + j];
        gi3_dot<128>(Wi, j, xs[0], xs[1], xs[2], gi[0], gi[1], gi[2]);
        const float bhj = bhh0[dir * 384 + j];
        for (int step = 0; step < 3; step++) {
            int t = dir ? 2 - step : step;
            float g = bhj + dot128_pf(Wh, j, hs[dir]);
            ghl[dir][j] = g;
            gil[dir][j] = gi[t];
            __syncthreads();
            if (j < 128) {
                float r = sigmoidf(gil[dir][j] + ghl[dir][j]);
                float z = sigmoidf(gil[dir][j + 128] + ghl[dir][j + 128]);
                float nn2 = tanhf(gil[dir][j + 256] + r * ghl[dir][j + 256]);
                float hnew = (1.f - z) * nn2 + z * hs[dir][j];
                hs[dir][j] = hnew;
                y0s[t][dir * 128 + j] = hnew;
                if (step == 2) fin01[dir][j] = hnew;
            }
            __syncthreads();
        }
    }
    if (j < 128) hs[dir][j] = 0.f;
    {
        const float* Wi = WihT1 + (size_t)dir * 256 * 384;
        const float* Wh = WhhT1 + (size_t)dir * 128 * 384;
        float gi[3];
        gi[0] = gi[1] = gi[2] = bih1[dir * 384 + j];
        gi3_dot<256>(Wi, j, y0s[0], y0s[1], y0s[2], gi[0], gi[1], gi[2]);
        const float bhj = bhh1[dir * 384 + j];
        __syncthreads();
        for (int step = 0; step < 3; step++) {
            int t = dir ? 2 - step : step;
            float g = bhj + dot128_pf(Wh, j, hs[dir]);
            ghl[dir][j] = g;
            gil[dir][j] = gi[t];
            __syncthreads();
            if (j < 128) {
                float r = sigmoidf(gil[dir][j] + ghl[dir][j]);
                float z = sigmoidf(gil[dir][j + 128] + ghl[dir][j + 128]);
                float nn2 = tanhf(gil[dir][j + 256] + r * ghl[dir][j + 256]);
                float hnew = (1.f - z) * nn2 + z * hs[dir][j];
                hs[dir][j] = hnew;
                if (step == 2) xs[dir][j] = hnew;
            }
            __syncthreads();
        }
    }
    if (tid < 128)
        out[(size_t)b * Hh + tid] = 0.25f * (fin01[0][tid] + fin01[1][tid] +
                                             xs[0][tid] + xs[1][tid]);
}

// ---------------------------------------------------------------------------
extern "C" void kernel_launch(void* const* d_in, const int* in_sizes, int n_in,
                              void* d_out, int out_size, void* d_ws, size_t ws_size,
                              hipStream_t stream) {
    const float* h      = (const float*)d_in[0];
    const int*   wid    = (const int*)d_in[1];
    const int*   src    = (const int*)d_in[2];
    const int*   dst    = (const int*)d_in[3];
    const int*   gid    = (const int*)d_in[4];
    const float* projW  = (const float*)d_in[5];
    const float* projB  = (const float*)d_in[6];
    const float* convWn = (const float*)d_in[7];
    const float* convBn = (const float*)d_in[8];
    const float* convAtt= (const float*)d_in[9];
    const float* convWs = (const float*)d_in[10];
    const float* convB  = (const float*)d_in[11];
    const float* convG  = (const float*)d_in[12];
    const float* convBe = (const float*)d_in[13];
    const float* Wih0   = (const float*)d_in[14];
    const float* Whh0   = (const float*)d_in[15];
    const float* bih0   = (const float*)d_in[16];
    const float* bhh0   = (const float*)d_in[17];
    const float* Wih1   = (const float*)d_in[18];
    const float* Whh1   = (const float*)d_in[19];
    const float* bih1   = (const float*)d_in[20];
    const float* bhh1   = (const float*)d_in[21];
    float* out = (float*)d_out;

    char* p = (char*)d_ws;
    auto align16 = [&]() { p = (char*)(((uintptr_t)p + 15) & ~(uintptr_t)15); };
    auto alloc_f = [&](size_t n) { align16(); float* r = (float*)p; p += n * sizeof(float); return r; };
    auto alloc_i = [&](size_t n) { align16(); int* r = (int*)p; p += n * sizeof(int); return r; };
    auto alloc_s = [&](size_t n) { align16(); unsigned short* r = (unsigned short*)p; p += n * sizeof(unsigned short); return r; };
    float* hcur  = alloc_f((size_t)Nn * 128);
    float* T     = alloc_f((size_t)Nn * 384);
    float* adbuf = alloc_f((size_t)Nn * 4);
    float* addbuf= alloc_f((size_t)Nn * 4);
    // contiguous zero region: reado | deg
    float* reado = alloc_f((size_t)3 * Bb * Hh);
    int* deg  = alloc_i(Nn);
    const size_t zero_bytes = (size_t)3 * Bb * Hh * sizeof(float) + Nn * sizeof(int);
    float* WihT0 = alloc_f((size_t)2 * 128 * 384);
    float* WhhT0 = alloc_f((size_t)2 * 128 * 384);
    float* WihT1 = alloc_f((size_t)2 * 256 * 384);
    float* WhhT1 = alloc_f((size_t)2 * 128 * 384);
    float* vavd  = alloc_f(1536);
    float* vc    = alloc_f(12);
    float* biasF = alloc_f(256);
    int* offs = alloc_i(Nn + 1);
    int* cur  = alloc_i(Nn);
    int* csrc = alloc_i(Ee);
    int* goffs = alloc_i(Bb + 1);
    unsigned short* hb = alloc_s((size_t)Nn * 128);   // bf16 hcur plane
    unsigned short* pBth = alloc_s(128 * 128);
    unsigned short* pBtl = alloc_s(128 * 128);
    unsigned short* WfTh[2] = { alloc_s(128 * 384), alloc_s(128 * 384) };
    unsigned short* WfTl[2] = { alloc_s(128 * 384), alloc_s(128 * 384) };

    hipMemsetAsync(reado, 0, zero_bytes, stream);

    PrepArgs pa;
    pa.projW = projW + (size_t)Vv * Hh;
    pa.convWn = convWn; pa.convWs = convWs; pa.convAtt = convAtt;
    pa.convBn = convBn; pa.convB = convB;
    pa.Wih0 = Wih0; pa.Whh0 = Whh0; pa.Wih1 = Wih1; pa.Whh1 = Whh1;
    pa.gid = gid; pa.dst = dst;
    pa.pBth = pBth; pa.pBtl = pBtl;
    pa.WfTh0 = WfTh[0]; pa.WfTl0 = WfTl[0]; pa.WfTh1 = WfTh[1]; pa.WfTl1 = WfTl[1];
    pa.vavd = vavd; pa.vc = vc; pa.biasF = biasF;
    pa.WihT0 = WihT0; pa.WhhT0 = WhhT0; pa.WihT1 = WihT1; pa.WhhT1 = WhhT1;
    pa.goffs = goffs; pa.deg = deg;
    const int prep_total = 16384 + 2 * 49152 + 1536 + 12 + 256 + 98304 + 98304 + 196608 + 98304 + Nn + Ee;
    prep_all<<<(prep_total + 255) / 256, 256, 0, stream>>>(pa);

    scan_offsets<<<1, 1024, 0, stream>>>(deg, offs, cur);
    fill_csr<<<1250, 256, 0, stream>>>(dst, src, cur, csrc);

    // projection + dots L0 + hb + readout0
    {
        GArgs g = {};
        g.A = h; g.Bth = pBth; g.Btl = pBtl; g.bias = projB;
        g.M = Nn; g.K = 128;
        g.wid = wid; g.projW = projW; g.hcur = hcur;
        g.gid = gid; g.reado = reado;
        g.vavd = vavd; g.vc = vc; g.adf = adbuf; g.addf = addbuf; g.hb = hb;
        gemm_fused<0><<<dim3(1, Nn / 32), 256, 0, stream>>>(g);
    }

    const int nwaveblocks = (Nn * 64 + 255) / 256;   // 5000
    for (int l = 0; l < 2; l++) {
        gat_gather<<<nwaveblocks, 256, 0, stream>>>(hb, (const float4*)adbuf, (const float4*)addbuf,
                                                    offs, csrc, T);
        {
            GArgs g = {};
            g.A = T; g.Bth = WfTh[l]; g.Btl = WfTl[l]; g.bias = biasF + l * 128;
            g.M = Nn; g.K = 384;
            g.deg = deg; g.gamma = convG + l * Hh; g.beta = convBe + l * Hh;
            g.hcur = hcur;
            g.gid = gid; g.reado = reado + (size_t)(l + 1) * Bb * Hh;
            if (l == 0) { g.vavd = vavd + 768; g.vc = vc + 6; g.adf = adbuf; g.addf = addbuf; g.hb = hb; }
            gemm_fused<2><<<dim3(1, Nn / 32), 256, 0, stream>>>(g);
        }
    }

    gru_all<<<Bb, 768, 0, stream>>>(reado, goffs, WihT0, WhhT0, bih0, bhh0,
                                    WihT1, WhhT1, bih1, bhh1, out);
}

// Round 12
// 401.837 us; speedup vs baseline: 1.1515x; 1.1515x over previous
//
#include <hip/hip_runtime.h>
#include <cstddef>
#include <cstdint>

// Problem constants (from reference)
static constexpr int Nn    = 20000;
static constexpr int Ee    = 320000;
static constexpr int Vv    = 100;
static constexpr int Hh    = 128;
static constexpr int HEADS = 3;
static constexpr int Bb    = 200;
static constexpr float NEG = 0.2f;
static constexpr float EPS = 1e-5f;

typedef short bf16x8 __attribute__((ext_vector_type(8)));
typedef float f32x4  __attribute__((ext_vector_type(4)));

__device__ inline unsigned short bf16_rne(float x) {
    unsigned u = __builtin_bit_cast(unsigned, x);
    u += 0x7FFFu + ((u >> 16) & 1u);
    return (unsigned short)(u >> 16);
}
__device__ inline float bf16_f(unsigned short h) {
    unsigned u = ((unsigned)h) << 16;
    return __builtin_bit_cast(float, u);
}
__device__ inline float bf_lo(unsigned u) { return __builtin_bit_cast(float, u << 16); }
__device__ inline float bf_hi(unsigned u) { return __builtin_bit_cast(float, u & 0xFFFF0000u); }
__device__ inline float lrelu(float a) { return a >= 0.f ? a : NEG * a; }
__device__ inline float sigmoidf(float x) { return 1.f / (1.f + __expf(-x)); }

// ---------------------------------------------------------------------------
// CSR scan + fill (hist lives in prep_all)
// ---------------------------------------------------------------------------
__global__ __launch_bounds__(1024) void scan_offsets(const int* __restrict__ deg,
                                                     int* __restrict__ offs,
                                                     int* __restrict__ cur) {
    __shared__ int sums[1024];
    const int tid = threadIdx.x;
    const int per = (Nn + 1023) >> 10;
    int begin = tid * per;
    int end = begin + per; if (end > Nn) end = Nn;
    if (begin > Nn) begin = Nn;
    int s = 0;
    for (int i = begin; i < end; i++) s += deg[i];
    sums[tid] = s;
    __syncthreads();
    for (int off = 1; off < 1024; off <<= 1) {
        int v = (tid >= off) ? sums[tid - off] : 0;
        __syncthreads();
        sums[tid] += v;
        __syncthreads();
    }
    int run = sums[tid] - s;
    for (int i = begin; i < end; i++) {
        offs[i] = run; cur[i] = run;
        run += deg[i];
    }
    if (end == Nn) offs[Nn] = run;
}

__global__ void fill_csr(const int* __restrict__ dst, const int* __restrict__ src,
                         int* __restrict__ cur, int* __restrict__ csrc) {
    for (int i = blockIdx.x * blockDim.x + threadIdx.x; i < Ee; i += gridDim.x * blockDim.x) {
        int p = atomicAdd(&cur[dst[i]], 1);
        csrc[p] = src[i];
    }
}

// ---------------------------------------------------------------------------
// Fused prep
// ---------------------------------------------------------------------------
struct PrepArgs {
    const float *projW, *convWn, *convWs, *convAtt, *convBn, *convB;
    const float *Wih0, *Whh0, *Wih1, *Whh1;
    const int *gid, *dst;
    unsigned short *pBth, *pBtl;
    unsigned short *WfTh0, *WfTl0, *WfTh1, *WfTl1;
    float *vavd, *vc, *biasF;
    float *WihT0, *WhhT0, *WihT1, *WhhT1;
    int *goffs, *deg;
};

__device__ inline void wsplit(const float* B, int K, int N, int idx,
                              unsigned short* Bth, unsigned short* Btl) {
    int k = idx / N, n = idx - k * N;
    float v = B[idx];
    unsigned short h = bf16_rne(v);
    unsigned short l = bf16_rne(v - bf16_f(h));
    Bth[(size_t)n * K + k] = h;
    Btl[(size_t)n * K + k] = l;
}
__device__ inline void gruT(const float* W, int K, int idx, float* WT) {
    int d = idx / (384 * K);
    int r = idx - d * 384 * K;
    int j = r / K, k = r - j * K;
    WT[(size_t)d * K * 384 + (size_t)k * 384 + j] = W[idx];
}

__global__ void prep_all(PrepArgs a) {
    int i = blockIdx.x * blockDim.x + threadIdx.x;
    if (i < 16384) { wsplit(a.projW, 128, 128, i, a.pBth, a.pBtl); return; } i -= 16384;
#pragma unroll
    for (int l = 0; l < 2; l++) {
        if (i < 49152) {
            int k = i >> 7, c = i & 127;
            int h = k >> 7, i_ = k & 127;
            const float* wn = a.convWn + (size_t)l * 49152 + (size_t)i_ * 384 + h * 128;
            const float* ws = a.convWs + (size_t)l * 49152 + (size_t)(h * 128) * 128 + c;
            float v = 0.f;
            for (int j = 0; j < 128; j++) v += wn[j] * ws[(size_t)j * 128];
            unsigned short hi = bf16_rne(v);
            unsigned short lo = bf16_rne(v - bf16_f(hi));
            unsigned short* th = l ? a.WfTh1 : a.WfTh0;
            unsigned short* tl = l ? a.WfTl1 : a.WfTl0;
            th[(size_t)c * 384 + k] = hi;
            tl[(size_t)c * 384 + k] = lo;
            return;
        }
        i -= 49152;
    }
    if (i < 1536) {
        int l = i / 768, r = i % 768;
        int sd = r / 384, rr = r % 384, h = rr >> 7, i_ = rr & 127;
        const float* wn = a.convWn + (size_t)l * 49152 + (size_t)i_ * 384 + h * 128;
        const float* at = a.convAtt + l * 768 + h * 256 + sd * 128;
        float v = 0.f;
        for (int j = 0; j < 128; j++) v += wn[j] * at[j];
        a.vavd[i] = v;
        return;
    } i -= 1536;
    if (i < 12) {
        int l = i / 6, r = i % 6, sd = r / 3, h = r % 3;
        const float* bn = a.convBn + l * 384 + h * 128;
        const float* at = a.convAtt + l * 768 + h * 256 + sd * 128;
        float v = 0.f;
        for (int j = 0; j < 128; j++) v += bn[j] * at[j];
        a.vc[i] = v;
        return;
    } i -= 12;
    if (i < 256) {
        int l = i >> 7, c = i & 127;
        const float* bn = a.convBn + l * 384;
        const float* ws = a.convWs + (size_t)l * 49152 + c;
        float v = a.convB[l * 128 + c];
        for (int k = 0; k < 384; k++) v += bn[k] * ws[(size_t)k * 128];
        a.biasF[i] = v;
        return;
    } i -= 256;
    if (i < 98304)  { gruT(a.Wih0, 128, i, a.WihT0); return; }  i -= 98304;
    if (i < 98304)  { gruT(a.Whh0, 128, i, a.WhhT0); return; }  i -= 98304;
    if (i < 196608) { gruT(a.Wih1, 256, i, a.WihT1); return; }  i -= 196608;
    if (i < 98304)  { gruT(a.Whh1, 128, i, a.WhhT1); return; }  i -= 98304;
    if (i < Nn) {
        int g = a.gid[i];
        if (i == 0) { for (int b = 0; b <= g; b++) a.goffs[b] = 0; }
        else { int pg = a.gid[i - 1]; for (int b = pg + 1; b <= g; b++) a.goffs[b] = i; }
        if (i == Nn - 1) { for (int b = g + 1; b <= Bb; b++) a.goffs[b] = Nn; }
        return;
    } i -= Nn;
    if (i < Ee) atomicAdd(&a.deg[a.dst[i]], 1);
}

// ---------------------------------------------------------------------------
// Split-bf16 MFMA GEMM with fused epilogues (unchanged from R10).
// ---------------------------------------------------------------------------
struct GArgs {
    const float* A; const unsigned short* Bth; const unsigned short* Btl;
    const float* bias; int M, K;
    const int* wid; const float* projW;
    const int* deg; const float* gamma; const float* beta;
    float* hcur;
    const int* gid; float* reado;
    const float* vavd; const float* vc;
    float* adf; float* addf;
    unsigned short* hb;
};

template <int MODE>
__global__ __launch_bounds__(256) void gemm_fused(GArgs a) {
    __shared__ unsigned short As_hi[32][40];
    __shared__ unsigned short As_lo[32][40];
    __shared__ unsigned short Bs_hi[128][40];
    __shared__ unsigned short Bs_lo[128][40];
    __shared__ float ytile[32][132];
    __shared__ float sred[6][32][4];
    __shared__ int sgid[32];
    const int tid  = threadIdx.x;
    const int row0 = blockIdx.y * 32;
    const int wn   = tid >> 6;
    const int L    = tid & 63;
    const int lrow = L & 15;
    const int lq   = L >> 4;
    const int K = a.K;

    f32x4 acc[2][2];
#pragma unroll
    for (int i = 0; i < 2; i++)
#pragma unroll
        for (int j = 0; j < 2; j++) acc[i][j] = (f32x4){0.f, 0.f, 0.f, 0.f};

    for (int kb = 0; kb < K; kb += 32) {
        {
            int m  = tid >> 3;
            int kq = (tid & 7) * 4;
            float4 v = *(const float4*)(a.A + (size_t)(row0 + m) * K + kb + kq);
            unsigned short h0 = bf16_rne(v.x), h1 = bf16_rne(v.y),
                           h2 = bf16_rne(v.z), h3 = bf16_rne(v.w);
            *(short4*)&As_hi[m][kq] = make_short4((short)h0, (short)h1, (short)h2, (short)h3);
            *(short4*)&As_lo[m][kq] = make_short4((short)bf16_rne(v.x - bf16_f(h0)),
                                                  (short)bf16_rne(v.y - bf16_f(h1)),
                                                  (short)bf16_rne(v.z - bf16_f(h2)),
                                                  (short)bf16_rne(v.w - bf16_f(h3)));
        }
        {
            int n  = tid >> 1;
            int kh = (tid & 1) * 16;
            const unsigned short* sh = a.Bth + (size_t)n * K + kb + kh;
            const unsigned short* sl = a.Btl + (size_t)n * K + kb + kh;
            *(float4*)&Bs_hi[n][kh]     = *(const float4*)sh;
            *(float4*)&Bs_hi[n][kh + 8] = *(const float4*)(sh + 8);
            *(float4*)&Bs_lo[n][kh]     = *(const float4*)sl;
            *(float4*)&Bs_lo[n][kh + 8] = *(const float4*)(sl + 8);
        }
        __syncthreads();
        bf16x8 ah[2], al[2], bh[2], bl[2];
#pragma unroll
        for (int mi = 0; mi < 2; mi++) {
            int r = mi * 16 + lrow;
            ah[mi] = *(const bf16x8*)&As_hi[r][lq * 8];
            al[mi] = *(const bf16x8*)&As_lo[r][lq * 8];
        }
#pragma unroll
        for (int ni = 0; ni < 2; ni++) {
            int r = wn * 32 + ni * 16 + lrow;
            bh[ni] = *(const bf16x8*)&Bs_hi[r][lq * 8];
            bl[ni] = *(const bf16x8*)&Bs_lo[r][lq * 8];
        }
#pragma unroll
        for (int mi = 0; mi < 2; mi++)
#pragma unroll
            for (int ni = 0; ni < 2; ni++) {
                acc[mi][ni] = __builtin_amdgcn_mfma_f32_16x16x32_bf16(ah[mi], bh[ni], acc[mi][ni], 0, 0, 0);
                acc[mi][ni] = __builtin_amdgcn_mfma_f32_16x16x32_bf16(ah[mi], bl[ni], acc[mi][ni], 0, 0, 0);
                acc[mi][ni] = __builtin_amdgcn_mfma_f32_16x16x32_bf16(al[mi], bh[ni], acc[mi][ni], 0, 0, 0);
            }
        __syncthreads();
    }

#pragma unroll
    for (int ni = 0; ni < 2; ni++) {
        float bb = a.bias[wn * 32 + ni * 16 + lrow];
#pragma unroll
        for (int mi = 0; mi < 2; mi++)
#pragma unroll
            for (int r = 0; r < 4; r++) acc[mi][ni][r] += bb;
    }

    if constexpr (MODE == 0) {
#pragma unroll
        for (int mi = 0; mi < 2; mi++)
#pragma unroll
            for (int r = 0; r < 4; r++) {
                int lr = mi * 16 + lq * 4 + r;
                int row = row0 + lr;
                int wi = a.wid[row];
#pragma unroll
                for (int ni = 0; ni < 2; ni++) {
                    int c = wn * 32 + ni * 16 + lrow;
                    float y = acc[mi][ni][r] + a.projW[(size_t)wi * 128 + c];
                    acc[mi][ni][r] = y;
                    a.hcur[(size_t)row * 128 + c] = y;
                    ytile[lr][c] = y;
                }
            }
    }

    if constexpr (MODE == 2) {
        __shared__ float red1[32][4], red2[32][4];
        float g4[2], be4[2];
#pragma unroll
        for (int ni = 0; ni < 2; ni++) {
            int c = wn * 32 + ni * 16 + lrow;
            g4[ni] = a.gamma[c]; be4[ni] = a.beta[c];
        }
#pragma unroll
        for (int mi = 0; mi < 2; mi++)
#pragma unroll
            for (int r = 0; r < 4; r++) {
                int lr = mi * 16 + lq * 4 + r;
                int row = row0 + lr;
                int dg = a.deg[row];
#pragma unroll
                for (int ni = 0; ni < 2; ni++) {
                    int c = wn * 32 + ni * 16 + lrow;
                    float hold = a.hcur[(size_t)row * 128 + c];
                    acc[mi][ni][r] = hold + (dg > 0 ? acc[mi][ni][r] : 0.f);
                }
            }
#pragma unroll
        for (int mi = 0; mi < 2; mi++)
#pragma unroll
            for (int r = 0; r < 4; r++) {
                float ps = acc[mi][0][r] + acc[mi][1][r];
#pragma unroll
                for (int o = 1; o < 16; o <<= 1) ps += __shfl_xor(ps, o, 64);
                if (lrow == 0) red1[mi * 16 + lq * 4 + r][wn] = ps;
            }
        __syncthreads();
#pragma unroll
        for (int mi = 0; mi < 2; mi++)
#pragma unroll
            for (int r = 0; r < 4; r++) {
                int lr = mi * 16 + lq * 4 + r;
                float mu = (red1[lr][0] + red1[lr][1] + red1[lr][2] + red1[lr][3]) * (1.f / 128.f);
                float qs = 0.f;
#pragma unroll
                for (int ni = 0; ni < 2; ni++) {
                    float dx = acc[mi][ni][r] - mu;
                    qs += dx * dx;
                }
#pragma unroll
                for (int o = 1; o < 16; o <<= 1) qs += __shfl_xor(qs, o, 64);
                if (lrow == 0) red2[lr][wn] = qs;
            }
        __syncthreads();
#pragma unroll
        for (int mi = 0; mi < 2; mi++)
#pragma unroll
            for (int r = 0; r < 4; r++) {
                int lr = mi * 16 + lq * 4 + r;
                int row = row0 + lr;
                float mu = (red1[lr][0] + red1[lr][1] + red1[lr][2] + red1[lr][3]) * (1.f / 128.f);
                float var = (red2[lr][0] + red2[lr][1] + red2[lr][2] + red2[lr][3]) * (1.f / 128.f);
                float rs = rsqrtf(var + EPS);
#pragma unroll
                for (int ni = 0; ni < 2; ni++) {
                    int c = wn * 32 + ni * 16 + lrow;
                    float y = fmaxf((acc[mi][ni][r] - mu) * rs * g4[ni] + be4[ni], 0.f);
                    acc[mi][ni][r] = y;
                    a.hcur[(size_t)row * 128 + c] = y;
                    ytile[lr][c] = y;
                }
            }
    }

    if (tid < 32) sgid[tid] = a.gid[row0 + tid];

    const bool dots = (a.vavd != nullptr);
    if (dots) {
        float vv0[6], vv1[6];
#pragma unroll
        for (int d = 0; d < 6; d++) {
            vv0[d] = a.vavd[d * 128 + wn * 32 + lrow];
            vv1[d] = a.vavd[d * 128 + wn * 32 + 16 + lrow];
        }
#pragma unroll
        for (int d = 0; d < 6; d++) {
#pragma unroll
            for (int mi = 0; mi < 2; mi++)
#pragma unroll
                for (int r = 0; r < 4; r++) {
                    float ps = acc[mi][0][r] * vv0[d] + acc[mi][1][r] * vv1[d];
#pragma unroll
                    for (int o = 1; o < 16; o <<= 1) ps += __shfl_xor(ps, o, 64);
                    if (lrow == 0) sred[d][mi * 16 + lq * 4 + r][wn] = ps;
                }
        }
    }
    __syncthreads();

    {
        int j = tid & 127, hh = tid >> 7;
        float sum = 0.f; int curg = -1;
        for (int r = hh * 16; r < hh * 16 + 16; r++) {
            int g = sgid[r];
            if (g != curg) {
                if (curg >= 0) atomicAdd(&a.reado[(size_t)curg * 128 + j], sum);
                sum = 0.f; curg = g;
            }
            sum += ytile[r][j];
        }
        if (curg >= 0) atomicAdd(&a.reado[(size_t)curg * 128 + j], sum);
    }

    if (dots) {
        if (tid < 192) {
            int row = tid & 31, d = tid >> 5;
            float s = sred[d][row][0] + sred[d][row][1] + sred[d][row][2] + sred[d][row][3]
                    + a.vc[d];
            int node = row0 + row;
            int sd = d / 3, h = d - sd * 3;
            float* dstp = sd ? a.addf : a.adf;
            dstp[(size_t)node * 4 + h] = s;
        }
        {
            int row = tid >> 3, c0 = (tid & 7) * 16;
            unsigned* dst = (unsigned*)(a.hb + (size_t)(row0 + row) * 128 + c0);
#pragma unroll
            for (int q = 0; q < 8; q++) {
                unsigned lo = bf16_rne(ytile[row][c0 + 2 * q]);
                unsigned hi = bf16_rne(ytile[row][c0 + 2 * q + 1]);
                dst[q] = lo | (hi << 16);
            }
        }
    }
}

// ---------------------------------------------------------------------------
// GAT gather (unchanged from R10)
// ---------------------------------------------------------------------------
__global__ __launch_bounds__(256) void gat_gather(const unsigned short* __restrict__ hb,
                                                  const float4* __restrict__ ad,
                                                  const float4* __restrict__ add,
                                                  const int* __restrict__ offs,
                                                  const int* __restrict__ csrc,
                                                  float* __restrict__ T) {
    __shared__ float4 slot[4][64];
    const int n = (blockIdx.x * 256 + threadIdx.x) >> 6;
    const int wv_ = threadIdx.x >> 6;
    const int L = threadIdx.x & 63;
    if (n >= Nn) return;
    const int start = offs[n];
    const int deg = offs[n + 1] - start;
    float2* o2 = (float2*)(T + (size_t)n * 384);
    if (deg == 0) {
        float2 z = make_float2(0.f, 0.f);
        o2[L] = z; o2[64 + L] = z; o2[128 + L] = z;
        return;
    }
    const float4 adn = add[n];
    float2 t0 = make_float2(0.f, 0.f), t1 = t0, t2 = t0;

    if (deg <= 64) {
        int sn = 0; float e0 = 0.f, e1 = 0.f, e2 = 0.f;
        if (L < deg) {
            sn = csrc[start + L];
            float4 a4 = ad[sn];
            e0 = __expf(lrelu(a4.x + adn.x));
            e1 = __expf(lrelu(a4.y + adn.y));
            e2 = __expf(lrelu(a4.z + adn.z));
        }
        float s0 = e0, s1 = e1, s2 = e2;
#pragma unroll
        for (int o = 32; o > 0; o >>= 1) {
            s0 += __shfl_xor(s0, o, 64);
            s1 += __shfl_xor(s1, o, 64);
            s2 += __shfl_xor(s2, o, 64);
        }
        slot[wv_][L] = make_float4(__builtin_bit_cast(float, sn),
                                   e0 / s0, e1 / s1, e2 / s2);
        __builtin_amdgcn_wave_barrier();
#pragma unroll 2
        for (int j = 0; j < deg; j++) {
            float4 sc = slot[wv_][j];
            int s_n = __builtin_bit_cast(int, sc.x);
            unsigned u = ((const unsigned*)(hb + (size_t)s_n * 128))[L];
            float x0 = bf_lo(u), x1 = bf_hi(u);
            t0.x += sc.y * x0; t0.y += sc.y * x1;
            t1.x += sc.z * x0; t1.y += sc.z * x1;
            t2.x += sc.w * x0; t2.y += sc.w * x1;
        }
    } else {
        float s0 = 0.f, s1 = 0.f, s2 = 0.f;
        for (int i = L; i < deg; i += 64) {
            int sn = csrc[start + i];
            float4 a4 = ad[sn];
            s0 += __expf(lrelu(a4.x + adn.x));
            s1 += __expf(lrelu(a4.y + adn.y));
            s2 += __expf(lrelu(a4.z + adn.z));
        }
#pragma unroll
        for (int o = 32; o > 0; o >>= 1) {
            s0 += __shfl_xor(s0, o, 64);
            s1 += __shfl_xor(s1, o, 64);
            s2 += __shfl_xor(s2, o, 64);
        }
        float i0 = 1.f / s0, i1 = 1.f / s1, i2 = 1.f / s2;
        for (int base = 0; base < deg; base += 64) {
            int cnt = deg - base; if (cnt > 64) cnt = 64;
            if (L < cnt) {
                int sn = csrc[start + base + L];
                float4 a4 = ad[sn];
                slot[wv_][L] = make_float4(__builtin_bit_cast(float, sn),
                                           __expf(lrelu(a4.x + adn.x)) * i0,
                                           __expf(lrelu(a4.y + adn.y)) * i1,
                                           __expf(lrelu(a4.z + adn.z)) * i2);
            }
            __builtin_amdgcn_wave_barrier();
            for (int j = 0; j < cnt; j++) {
                float4 sc = slot[wv_][j];
                int s_n = __builtin_bit_cast(int, sc.x);
                unsigned u = ((const unsigned*)(hb + (size_t)s_n * 128))[L];
                float x0 = bf_lo(u), x1 = bf_hi(u);
                t0.x += sc.y * x0; t0.y += sc.y * x1;
                t1.x += sc.z * x0; t1.y += sc.z * x1;
                t2.x += sc.w * x0; t2.y += sc.w * x1;
            }
            __builtin_amdgcn_wave_barrier();
        }
    }
    o2[L] = t0; o2[64 + L] = t1; o2[128 + L] = t2;
}

// ---------------------------------------------------------------------------
// GRU, batched: one block = BPER batch elements x both dirs, 768 threads
// (2 dirs x 384 gate-units). Thread j accumulates BPER (x3 timesteps in the
// gi pass) independent chains -> ILP + weight reuse; plain loops, no manual
// register buffers (R11's spill lesson). r,z gates store gi+gh summed; the
// n gate keeps gi and gh separate (n = tanh(gi_n + r*gh_n)).
// ---------------------------------------------------------------------------
static constexpr int BPER = 4;   // 200 % 4 == 0 -> 50 blocks

__global__ __launch_bounds__(768) void gru_all(const float* __restrict__ reado,
                                               const int* __restrict__ goffs,
                                               const float* __restrict__ WihT0,
                                               const float* __restrict__ WhhT0,
                                               const float* __restrict__ bih0,
                                               const float* __restrict__ bhh0,
                                               const float* __restrict__ WihT1,
                                               const float* __restrict__ WhhT1,
                                               const float* __restrict__ bih1,
                                               const float* __restrict__ bhh1,
                                               float* __restrict__ out) {
    const int b0 = blockIdx.x * BPER;
    const int tid = threadIdx.x;
    const int dir = tid / 384;
    const int j = tid - dir * 384;
    __shared__ float xs[3][BPER][128];       // inputs; planes [0..1] reused as fin23
    __shared__ float y0s[3][BPER][256];
    __shared__ float hs[2][BPER][128];
    __shared__ float ghS[2][BPER][384];      // r,z: gi+gh ; n: gh only
    __shared__ float giN[2][BPER][128];      // gi of the n gate (j in [256,384))
    __shared__ float fin01[2][BPER][128];
    for (int idx = tid; idx < 3 * BPER * 128; idx += 768) {
        int t = idx / (BPER * 128);
        int bb = (idx / 128) % BPER;
        int jj = idx & 127;
        int b = b0 + bb;
        int cnt = goffs[b + 1] - goffs[b];
        float invc = 1.f / fmaxf((float)cnt, 1.f);
        xs[t][bb][jj] = reado[(size_t)t * Bb * Hh + (size_t)b * Hh + jj] * invc;
    }
    for (int idx = tid; idx < 2 * BPER * 128; idx += 768)
        ((float*)hs)[idx] = 0.f;
    __syncthreads();
    // ---- layer 0 ----
    {
        const float* Wi = WihT0 + (size_t)dir * 128 * 384;
        const float* Wh = WhhT0 + (size_t)dir * 128 * 384;
        float gi[3][BPER];
        float bij = bih0[dir * 384 + j];
#pragma unroll
        for (int t = 0; t < 3; t++)
#pragma unroll
            for (int bb = 0; bb < BPER; bb++) gi[t][bb] = bij;
        for (int k = 0; k < 128; k++) {
            float w = Wi[(size_t)k * 384 + j];
#pragma unroll
            for (int t = 0; t < 3; t++)
#pragma unroll
                for (int bb = 0; bb < BPER; bb++) gi[t][bb] += w * xs[t][bb][k];
        }
        const float bhj = bhh0[dir * 384 + j];
        for (int step = 0; step < 3; step++) {
            int t = dir ? 2 - step : step;
            float g[BPER];
#pragma unroll
            for (int bb = 0; bb < BPER; bb++) g[bb] = bhj;
            for (int k = 0; k < 128; k++) {
                float w = Wh[(size_t)k * 384 + j];
#pragma unroll
                for (int bb = 0; bb < BPER; bb++) g[bb] += w * hs[dir][bb][k];
            }
#pragma unroll
            for (int bb = 0; bb < BPER; bb++) {
                if (j < 256) ghS[dir][bb][j] = gi[t][bb] + g[bb];
                else { ghS[dir][bb][j] = g[bb]; giN[dir][bb][j - 256] = gi[t][bb]; }
            }
            __syncthreads();
            if (j < 128) {
#pragma unroll
                for (int bb = 0; bb < BPER; bb++) {
                    float r = sigmoidf(ghS[dir][bb][j]);
                    float z = sigmoidf(ghS[dir][bb][j + 128]);
                    float nn2 = tanhf(giN[dir][bb][j] + r * ghS[dir][bb][j + 256]);
                    float hnew = (1.f - z) * nn2 + z * hs[dir][bb][j];
                    hs[dir][bb][j] = hnew;
                    y0s[t][bb][dir * 128 + j] = hnew;
                    if (step == 2) fin01[dir][bb][j] = hnew;
                }
            }
            __syncthreads();
        }
    }
    // ---- layer 1 ----
    if (j < 128) {
#pragma unroll
        for (int bb = 0; bb < BPER; bb++) hs[dir][bb][j] = 0.f;
    }
    __syncthreads();
    {
        const float* Wi = WihT1 + (size_t)dir * 256 * 384;
        const float* Wh = WhhT1 + (size_t)dir * 128 * 384;
        float gi[3][BPER];
        float bij = bih1[dir * 384 + j];
#pragma unroll
        for (int t = 0; t < 3; t++)
#pragma unroll
            for (int bb = 0; bb < BPER; bb++) gi[t][bb] = bij;
        for (int k = 0; k < 256; k++) {
            float w = Wi[(size_t)k * 384 + j];
#pragma unroll
            for (int t = 0; t < 3; t++)
#pragma unroll
                for (int bb = 0; bb < BPER; bb++) gi[t][bb] += w * y0s[t][bb][k];
        }
        const float bhj = bhh1[dir * 384 + j];
        for (int step = 0; step < 3; step++) {
            int t = dir ? 2 - step : step;
            float g[BPER];
#pragma unroll
            for (int bb = 0; bb < BPER; bb++) g[bb] = bhj;
            for (int k = 0; k < 128; k++) {
                float w = Wh[(size_t)k * 384 + j];
#pragma unroll
                for (int bb = 0; bb < BPER; bb++) g[bb] += w * hs[dir][bb][k];
            }
#pragma unroll
            for (int bb = 0; bb < BPER; bb++) {
                if (j < 256) ghS[dir][bb][j] = gi[t][bb] + g[bb];
                else { ghS[dir][bb][j] = g[bb]; giN[dir][bb][j - 256] = gi[t][bb]; }
            }
            __syncthreads();
            if (j < 128) {
#pragma unroll
                for (int bb = 0; bb < BPER; bb++) {
                    float r = sigmoidf(ghS[dir][bb][j]);
                    float z = sigmoidf(ghS[dir][bb][j + 128]);
                    float nn2 = tanhf(giN[dir][bb][j] + r * ghS[dir][bb][j + 256]);
                    float hnew = (1.f - z) * nn2 + z * hs[dir][bb][j];
                    hs[dir][bb][j] = hnew;
                    if (step == 2) xs[dir][bb][j] = hnew;   // fin23
                }
            }
            __syncthreads();
        }
    }
    for (int idx = tid; idx < BPER * 128; idx += 768) {
        int bb = idx >> 7, jj = idx & 127;
        out[(size_t)(b0 + bb) * Hh + jj] =
            0.25f * (fin01[0][bb][jj] + fin01[1][bb][jj] + xs[0][bb][jj] + xs[1][bb][jj]);
    }
}

// ---------------------------------------------------------------------------
extern "C" void kernel_launch(void* const* d_in, const int* in_sizes, int n_in,
                              void* d_out, int out_size, void* d_ws, size_t ws_size,
                              hipStream_t stream) {
    const float* h      = (const float*)d_in[0];
    const int*   wid    = (const int*)d_in[1];
    const int*   src    = (const int*)d_in[2];
    const int*   dst    = (const int*)d_in[3];
    const int*   gid    = (const int*)d_in[4];
    const float* projW  = (const float*)d_in[5];
    const float* projB  = (const float*)d_in[6];
    const float* convWn = (const float*)d_in[7];
    const float* convBn = (const float*)d_in[8];
    const float* convAtt= (const float*)d_in[9];
    const float* convWs = (const float*)d_in[10];
    const float* convB  = (const float*)d_in[11];
    const float* convG  = (const float*)d_in[12];
    const float* convBe = (const float*)d_in[13];
    const float* Wih0   = (const float*)d_in[14];
    const float* Whh0   = (const float*)d_in[15];
    const float* bih0   = (const float*)d_in[16];
    const float* bhh0   = (const float*)d_in[17];
    const float* Wih1   = (const float*)d_in[18];
    const float* Whh1   = (const float*)d_in[19];
    const float* bih1   = (const float*)d_in[20];
    const float* bhh1   = (const float*)d_in[21];
    float* out = (float*)d_out;

    char* p = (char*)d_ws;
    auto align16 = [&]() { p = (char*)(((uintptr_t)p + 15) & ~(uintptr_t)15); };
    auto alloc_f = [&](size_t n) { align16(); float* r = (float*)p; p += n * sizeof(float); return r; };
    auto alloc_i = [&](size_t n) { align16(); int* r = (int*)p; p += n * sizeof(int); return r; };
    auto alloc_s = [&](size_t n) { align16(); unsigned short* r = (unsigned short*)p; p += n * sizeof(unsigned short); return r; };
    float* hcur  = alloc_f((size_t)Nn * 128);
    float* T     = alloc_f((size_t)Nn * 384);
    float* adbuf = alloc_f((size_t)Nn * 4);
    float* addbuf= alloc_f((size_t)Nn * 4);
    float* reado = alloc_f((size_t)3 * Bb * Hh);
    int* deg  = alloc_i(Nn);
    const size_t zero_bytes = (size_t)3 * Bb * Hh * sizeof(float) + Nn * sizeof(int);
    float* WihT0 = alloc_f((size_t)2 * 128 * 384);
    float* WhhT0 = alloc_f((size_t)2 * 128 * 384);
    float* WihT1 = alloc_f((size_t)2 * 256 * 384);
    float* WhhT1 = alloc_f((size_t)2 * 128 * 384);
    float* vavd  = alloc_f(1536);
    float* vc    = alloc_f(12);
    float* biasF = alloc_f(256);
    int* offs = alloc_i(Nn + 1);
    int* cur  = alloc_i(Nn);
    int* csrc = alloc_i(Ee);
    int* goffs = alloc_i(Bb + 1);
    unsigned short* hb = alloc_s((size_t)Nn * 128);
    unsigned short* pBth = alloc_s(128 * 128);
    unsigned short* pBtl = alloc_s(128 * 128);
    unsigned short* WfTh[2] = { alloc_s(128 * 384), alloc_s(128 * 384) };
    unsigned short* WfTl[2] = { alloc_s(128 * 384), alloc_s(128 * 384) };

    hipMemsetAsync(reado, 0, zero_bytes, stream);

    PrepArgs pa;
    pa.projW = projW + (size_t)Vv * Hh;
    pa.convWn = convWn; pa.convWs = convWs; pa.convAtt = convAtt;
    pa.convBn = convBn; pa.convB = convB;
    pa.Wih0 = Wih0; pa.Whh0 = Whh0; pa.Wih1 = Wih1; pa.Whh1 = Whh1;
    pa.gid = gid; pa.dst = dst;
    pa.pBth = pBth; pa.pBtl = pBtl;
    pa.WfTh0 = WfTh[0]; pa.WfTl0 = WfTl[0]; pa.WfTh1 = WfTh[1]; pa.WfTl1 = WfTl[1];
    pa.vavd = vavd; pa.vc = vc; pa.biasF = biasF;
    pa.WihT0 = WihT0; pa.WhhT0 = WhhT0; pa.WihT1 = WihT1; pa.WhhT1 = WhhT1;
    pa.goffs = goffs; pa.deg = deg;
    const int prep_total = 16384 + 2 * 49152 + 1536 + 12 + 256 + 98304 + 98304 + 196608 + 98304 + Nn + Ee;
    prep_all<<<(prep_total + 255) / 256, 256, 0, stream>>>(pa);

    scan_offsets<<<1, 1024, 0, stream>>>(deg, offs, cur);
    fill_csr<<<1250, 256, 0, stream>>>(dst, src, cur, csrc);

    // projection + dots L0 + hb + readout0
    {
        GArgs g = {};
        g.A = h; g.Bth = pBth; g.Btl = pBtl; g.bias = projB;
        g.M = Nn; g.K = 128;
        g.wid = wid; g.projW = projW; g.hcur = hcur;
        g.gid = gid; g.reado = reado;
        g.vavd = vavd; g.vc = vc; g.adf = adbuf; g.addf = addbuf; g.hb = hb;
        gemm_fused<0><<<dim3(1, Nn / 32), 256, 0, stream>>>(g);
    }

    const int nwaveblocks = (Nn * 64 + 255) / 256;   // 5000
    for (int l = 0; l < 2; l++) {
        gat_gather<<<nwaveblocks, 256, 0, stream>>>(hb, (const float4*)adbuf, (const float4*)addbuf,
                                                    offs, csrc, T);
        {
            GArgs g = {};
            g.A = T; g.Bth = WfTh[l]; g.Btl = WfTl[l]; g.bias = biasF + l * 128;
            g.M = Nn; g.K = 384;
            g.deg = deg; g.gamma = convG + l * Hh; g.beta = convBe + l * Hh;
            g.hcur = hcur;
            g.gid = gid; g.reado = reado + (size_t)(l + 1) * Bb * Hh;
            if (l == 0) { g.vavd = vavd + 768; g.vc = vc + 6; g.adf = adbuf; g.addf = addbuf; g.hb = hb; }
            gemm_fused<2><<<dim3(1, Nn / 32), 256, 0, stream>>>(g);
        }
    }

    gru_all<<<Bb / BPER, 768, 0, stream>>>(reado, goffs, WihT0, WhhT0, bih0, bhh0,
                                           WihT1, WhhT1, bih1, bhh1, out);
}